// Round 2
// baseline (3639.922 us; speedup 1.0000x reference)
//
#include <hip/hip_runtime.h>
#include <hip/hip_bf16.h>
#include <math.h>

#define DD 256
#define NL 3
#define NHD 8
#define NPT 8
#define HDIM 32
#define NQ 1024
#define BB 8
#define HH 200
#define WW 200
#define MROWS (BB*NQ)   // 8192

__device__ __forceinline__ float b2f(const __hip_bfloat16 x) { return __bfloat162float(x); }

// ---------------------------------------------------------------- dtype detect
// bf16 randn data never has exponent-field >= 0xC0 (|x| >= 2^65); fp32 data read
// as shorts has uniform-random mantissa halves -> ~12% hit. flag=1 => fp32 inputs.
__global__ __launch_bounds__(256) void detect_kernel(const unsigned short* __restrict__ ba,
                                                     int* __restrict__ flag)
{
    __shared__ int hit;
    if (threadIdx.x == 0) hit = 0;
    __syncthreads();
    int local = 0;
    for (int i = threadIdx.x; i < 262144; i += 256) {
        unsigned e = (ba[i] >> 7) & 0xFF;
        if (e >= 0xC0) local = 1;
    }
    if (local) atomicOr(&hit, 1);
    __syncthreads();
    if (threadIdx.x == 0) *flag = hit;
}

// ---------------------------------------------------------------- param convert
struct Tab {
    const void* src[40];
    unsigned cum[41];
};

__global__ __launch_bounds__(256) void convert_kernel(Tab t, const int* __restrict__ flag,
                                                      float* __restrict__ arena, unsigned total)
{
    unsigned g = blockIdx.x * 256 + threadIdx.x;
    if (g >= total) return;
    int lo = 0, hi = 39;
    while (lo < hi) {
        int mid = (lo + hi + 1) >> 1;
        if (g >= t.cum[mid]) lo = mid; else hi = mid - 1;
    }
    unsigned idx = g - t.cum[lo];
    float v;
    if (*flag) v = ((const float*)t.src[lo])[idx];
    else       v = b2f(((const __hip_bfloat16*)t.src[lo])[idx]);
    arena[g] = v;
}

// ---------------------------------------------------------------- transpose (optional)
// bev [B,256,H,W] (bf16 or fp32 per flag) -> bevT [B,H,W,256] bf16.
__global__ __launch_bounds__(256) void transpose_kernel(const void* __restrict__ bevv,
                                                        const int* __restrict__ flag,
                                                        __hip_bfloat16* __restrict__ bevT)
{
    const int t = blockIdx.x;
    const int xc = t & 7;
    const int y  = (t >> 3) % HH;
    const int b  = t / (8 * HH);
    const int c  = threadIdx.x;
    const int x0 = xc * 25;
    const size_t src = (((size_t)b * DD + c) * HH + y) * WW + x0;
    const size_t dst = (((size_t)b * HH + y) * WW + x0) * DD + c;
    __hip_bfloat16 tmp[25];
    if (*flag) {
        const float* p = (const float*)bevv;
        #pragma unroll
        for (int x = 0; x < 25; ++x) tmp[x] = __float2bfloat16(p[src + x]);
    } else {
        const __hip_bfloat16* p = (const __hip_bfloat16*)bevv;
        #pragma unroll
        for (int x = 0; x < 25; ++x) tmp[x] = p[src + x];
    }
    #pragma unroll
    for (int x = 0; x < 25; ++x) bevT[dst + (size_t)x * DD] = tmp[x];
}

// ---------------------------------------------------------------- init
__global__ __launch_bounds__(256) void init_out_kernel(const float* __restrict__ ba,
                                                       float* __restrict__ out)
{
    int i = blockIdx.x * 256 + threadIdx.x;
    out[i] = ba[i & (NQ * DD - 1)];
}

__global__ __launch_bounds__(256) void init_ref_kernel(const float* __restrict__ rp,
                                                       float* __restrict__ ref)
{
    int i = blockIdx.x * 256 + threadIdx.x;
    ref[i] = tanhf(rp[i & (NQ * 2 - 1)]);
}

// ---------------------------------------------------------------- sine embed
__global__ __launch_bounds__(256) void sine_kernel(const float* __restrict__ refpos,
                                                   float* __restrict__ out)
{
    const int bn = blockIdx.x, tid = threadIdx.x;
    const float p = refpos[bn * 2 + (tid < 128 ? 1 : 0)];
    const int j = tid & 127;
    const int k = j >> 1;
    const float t = p * 6.2831853071795864f * exp2f(-(float)k * (4.3219280948873623f / 64.f));
    out[(size_t)bn * DD + tid] = (j & 1) ? cosf(t) : sinf(t);
}

// ---------------------------------------------------------------- GEMM (fp32, C = act(A@W^T + b))
template<int RELU_>
__global__ __launch_bounds__(256) void gemm_kernel(const float* __restrict__ A,
                                                   const float* __restrict__ W,
                                                   const float* __restrict__ bias,
                                                   float* __restrict__ C,
                                                   int M, int N, int K)
{
    __shared__ float As[16][68];
    __shared__ float Bs[16][68];
    const int tid = threadIdx.x;
    const int tx = tid & 15, ty = tid >> 4;
    const int n0 = blockIdx.x * 64, m0 = blockIdx.y * 64;
    const int lrow = tid >> 2, lk = (tid & 3) * 4;
    float acc[4][4] = {};
    for (int k0 = 0; k0 < K; k0 += 16) {
        float4 av = *reinterpret_cast<const float4*>(A + (size_t)(m0 + lrow) * K + k0 + lk);
        float4 wv = *reinterpret_cast<const float4*>(W + (size_t)(n0 + lrow) * K + k0 + lk);
        As[lk + 0][lrow] = av.x; As[lk + 1][lrow] = av.y;
        As[lk + 2][lrow] = av.z; As[lk + 3][lrow] = av.w;
        Bs[lk + 0][lrow] = wv.x; Bs[lk + 1][lrow] = wv.y;
        Bs[lk + 2][lrow] = wv.z; Bs[lk + 3][lrow] = wv.w;
        __syncthreads();
        #pragma unroll
        for (int kk = 0; kk < 16; ++kk) {
            float4 a = *reinterpret_cast<const float4*>(&As[kk][ty * 4]);
            float4 b = *reinterpret_cast<const float4*>(&Bs[kk][tx * 4]);
            float aa[4] = {a.x, a.y, a.z, a.w};
            float bb[4] = {b.x, b.y, b.z, b.w};
            #pragma unroll
            for (int i = 0; i < 4; ++i)
                #pragma unroll
                for (int j = 0; j < 4; ++j)
                    acc[i][j] = fmaf(aa[i], bb[j], acc[i][j]);
        }
        __syncthreads();
    }
    #pragma unroll
    for (int i = 0; i < 4; ++i) {
        float4 o;
        float* op = &o.x;
        #pragma unroll
        for (int j = 0; j < 4; ++j) {
            float v = acc[i][j] + bias[n0 + tx * 4 + j];
            if (RELU_) v = fmaxf(v, 0.f);
            op[j] = v;
        }
        *reinterpret_cast<float4*>(C + (size_t)(m0 + ty * 4 + i) * N + n0 + tx * 4) = o;
    }
}

// ---------------------------------------------------------------- elementwise
__global__ __launch_bounds__(256) void mul_kernel(float* __restrict__ a, const float* __restrict__ b)
{
    int i = blockIdx.x * 256 + threadIdx.x;
    float4 x = reinterpret_cast<float4*>(a)[i];
    float4 y = reinterpret_cast<const float4*>(b)[i];
    x.x *= y.x; x.y *= y.y; x.z *= y.z; x.w *= y.w;
    reinterpret_cast<float4*>(a)[i] = x;
}

__global__ __launch_bounds__(256) void add_kernel(float* __restrict__ dst, const float* __restrict__ a,
                                                  const float* __restrict__ b)
{
    int i = blockIdx.x * 256 + threadIdx.x;
    float4 x = reinterpret_cast<const float4*>(a)[i];
    float4 y = reinterpret_cast<const float4*>(b)[i];
    x.x += y.x; x.y += y.y; x.z += y.z; x.w += y.w;
    reinterpret_cast<float4*>(dst)[i] = x;
}

// ---------------------------------------------------------------- self-attention
__global__ __launch_bounds__(256) void attn_kernel(const float* __restrict__ Q,
                                                   const float* __restrict__ Kb,
                                                   const float* __restrict__ Vb,
                                                   float* __restrict__ O)
{
    __shared__ float Ks[64][32];
    __shared__ float Vs[64][32];
    const int tid = threadIdx.x;
    const int bid = blockIdx.x;
    const int bh = bid >> 2;
    const int b = bh >> 3, h = bh & 7;
    const int n = ((bid & 3) << 8) + tid;
    const size_t qbase = ((size_t)(b * NQ + n)) * DD + h * HDIM;
    float q[32];
    #pragma unroll
    for (int dv = 0; dv < 8; ++dv) {
        float4 qq = *reinterpret_cast<const float4*>(Q + qbase + dv * 4);
        q[dv * 4 + 0] = qq.x * 0.17677669529663687f;
        q[dv * 4 + 1] = qq.y * 0.17677669529663687f;
        q[dv * 4 + 2] = qq.z * 0.17677669529663687f;
        q[dv * 4 + 3] = qq.w * 0.17677669529663687f;
    }
    float m = -3.0e38f, lsum = 0.f;
    float acc[32];
    #pragma unroll
    for (int d = 0; d < 32; ++d) acc[d] = 0.f;
    for (int kt = 0; kt < NQ; kt += 64) {
        #pragma unroll
        for (int r = 0; r < 8; ++r) {
            int idx = r * 256 + tid;
            int j = idx >> 5, d = idx & 31;
            size_t g = ((size_t)(b * NQ + kt + j)) * DD + h * HDIM + d;
            Ks[j][d] = Kb[g];
            Vs[j][d] = Vb[g];
        }
        __syncthreads();
        for (int j = 0; j < 64; ++j) {
            float s0 = 0.f, s1 = 0.f, s2 = 0.f, s3 = 0.f;
            #pragma unroll
            for (int dv = 0; dv < 8; ++dv) {
                float4 kv = reinterpret_cast<const float4*>(&Ks[j][0])[dv];
                s0 = fmaf(q[dv * 4 + 0], kv.x, s0);
                s1 = fmaf(q[dv * 4 + 1], kv.y, s1);
                s2 = fmaf(q[dv * 4 + 2], kv.z, s2);
                s3 = fmaf(q[dv * 4 + 3], kv.w, s3);
            }
            float s = (s0 + s1) + (s2 + s3);
            if (s > m) {
                float corr = __expf(m - s);
                lsum *= corr;
                #pragma unroll
                for (int d = 0; d < 32; ++d) acc[d] *= corr;
                m = s;
            }
            float p = __expf(s - m);
            lsum += p;
            #pragma unroll
            for (int dv = 0; dv < 8; ++dv) {
                float4 vv = reinterpret_cast<const float4*>(&Vs[j][0])[dv];
                acc[dv * 4 + 0] = fmaf(p, vv.x, acc[dv * 4 + 0]);
                acc[dv * 4 + 1] = fmaf(p, vv.y, acc[dv * 4 + 1]);
                acc[dv * 4 + 2] = fmaf(p, vv.z, acc[dv * 4 + 2]);
                acc[dv * 4 + 3] = fmaf(p, vv.w, acc[dv * 4 + 3]);
            }
        }
        __syncthreads();
    }
    float inv = 1.f / lsum;
    #pragma unroll
    for (int d = 0; d < 32; ++d) O[qbase + d] = acc[d] * inv;
}

// ---------------------------------------------------------------- layernorm of (X+R)
__global__ __launch_bounds__(256) void ln_kernel(const float* __restrict__ X,
                                                 const float* __restrict__ R,
                                                 const float* __restrict__ g,
                                                 const float* __restrict__ bta,
                                                 float* __restrict__ Y)
{
    __shared__ float red[4], red2[4];
    const int row = blockIdx.x, tid = threadIdx.x;
    float x = X[(size_t)row * DD + tid] + R[(size_t)row * DD + tid];
    float s = x;
    for (int off = 32; off; off >>= 1) s += __shfl_down(s, off, 64);
    const int wid = tid >> 6, lane = tid & 63;
    if (lane == 0) red[wid] = s;
    __syncthreads();
    float mean = (red[0] + red[1] + red[2] + red[3]) * (1.f / 256.f);
    float c = x - mean;
    float s2 = c * c;
    for (int off = 32; off; off >>= 1) s2 += __shfl_down(s2, off, 64);
    if (lane == 0) red2[wid] = s2;
    __syncthreads();
    float var = (red2[0] + red2[1] + red2[2] + red2[3]) * (1.f / 256.f);
    Y[(size_t)row * DD + tid] = c * rsqrtf(var + 1e-5f) * g[tid] + bta[tid];
}

// ---------------------------------------------------------------- aw softmax over P=8
__global__ __launch_bounds__(256) void awsm_kernel(float* __restrict__ awl)
{
    int i = blockIdx.x * 256 + threadIdx.x;
    size_t base = (size_t)i * 8;
    float v[8];
    float mx = -3.0e38f;
    #pragma unroll
    for (int p = 0; p < 8; ++p) { v[p] = awl[base + p]; mx = fmaxf(mx, v[p]); }
    float ssum = 0.f;
    #pragma unroll
    for (int p = 0; p < 8; ++p) { v[p] = __expf(v[p] - mx); ssum += v[p]; }
    float inv = 1.f / ssum;
    #pragma unroll
    for (int p = 0; p < 8; ++p) awl[base + p] = v[p] * inv;
}

// ---------------------------------------------------------------- deformable sampling
// One block per (b,n). thread = (h = tid>>5, c = tid&31).
// mode: 2 = bevT channels-last bf16; 1 = raw fp32; 0 = raw bf16.
__global__ __launch_bounds__(256) void sample_kernel(const void* __restrict__ bevraw,
                                                     const __hip_bfloat16* __restrict__ bevT,
                                                     const int* __restrict__ flag, int useT,
                                                     const float* __restrict__ refpos,
                                                     const float* __restrict__ OFF,
                                                     const float* __restrict__ AW,
                                                     const float* __restrict__ vpw,
                                                     const float* __restrict__ vpb,
                                                     float* __restrict__ CA)
{
    __shared__ float vpsT[1024];   // vpsT[cc*32+c'] = vpw[c'][cc]
    __shared__ float vpbs[32];
    __shared__ float aggs[256];
    const int bn = blockIdx.x;
    const int b = bn >> 10;
    const int tid = threadIdx.x;
    const int h = tid >> 5, c = tid & 31;
    const int mode = useT ? 2 : (*flag ? 1 : 0);
    for (int idx = tid; idx < 1024; idx += 256)
        vpsT[idx] = vpw[(idx & 31) * 32 + (idx >> 5)];
    if (tid < 32) vpbs[tid] = vpb[tid];
    const float rx = refpos[bn * 2 + 0], ry = refpos[bn * 2 + 1];
    const float* fbev = (const float*)bevraw;
    const __hip_bfloat16* hbev = (const __hip_bfloat16*)bevraw;
    float agg = 0.f;
    #pragma unroll
    for (int p = 0; p < 8; ++p) {
        const float ox = OFF[(size_t)bn * 128 + h * 16 + p * 2 + 0];
        const float oy = OFF[(size_t)bn * 128 + h * 16 + p * 2 + 1];
        const float a = AW[(size_t)bn * 64 + h * 8 + p];
        float x = (rx + ox * (1.f / 200.f) + 1.f) * 100.f - 0.5f;
        float y = (ry + oy * (1.f / 200.f) + 1.f) * 100.f - 0.5f;
        float x0f = floorf(x), y0f = floorf(y);
        int x0 = (int)x0f, y0 = (int)y0f;
        float wx1 = x - x0f, wx0 = 1.f - wx1;
        float wy1 = y - y0f, wy0 = 1.f - wy1;
        int xs[2] = { x0, x0 + 1 };
        int ys[2] = { y0, y0 + 1 };
        float wxs[2] = { wx0, wx1 };
        float wys[2] = { wy0, wy1 };
        float v = 0.f;
        #pragma unroll
        for (int cy = 0; cy < 2; ++cy)
            #pragma unroll
            for (int cx = 0; cx < 2; ++cx) {
                int xi = xs[cx], yi = ys[cy];
                if (xi >= 0 && xi < WW && yi >= 0 && yi < HH) {
                    float val;
                    if (mode == 2)
                        val = b2f(bevT[(((size_t)(b * HH + yi)) * WW + xi) * DD + h * HDIM + c]);
                    else {
                        size_t addr = (((size_t)(b * DD + h * HDIM + c)) * HH + yi) * WW + xi;
                        val = (mode == 1) ? fbev[addr] : b2f(hbev[addr]);
                    }
                    v = fmaf(wxs[cx] * wys[cy], val, v);
                }
            }
        agg = fmaf(a, v, agg);
    }
    aggs[tid] = agg;
    __syncthreads();
    float o = vpbs[c];
    #pragma unroll
    for (int cc = 0; cc < 32; ++cc)
        o = fmaf(vpsT[cc * 32 + c], aggs[h * 32 + cc], o);
    CA[(size_t)bn * DD + tid] = o;
}

// ---------------------------------------------------------------- ref_pos refine
__global__ __launch_bounds__(256) void refine_kernel(const float* __restrict__ H2,
                                                     const float* __restrict__ w3,
                                                     const float* __restrict__ b3,
                                                     float* __restrict__ refpos)
{
    const int tid = threadIdx.x;
    const int wid = tid >> 6, lane = tid & 63;
    const int row = blockIdx.x * 4 + wid;
    const float4 hv = *reinterpret_cast<const float4*>(H2 + (size_t)row * DD + lane * 4);
    const float4 w0 = *reinterpret_cast<const float4*>(w3 + lane * 4);
    const float4 w1 = *reinterpret_cast<const float4*>(w3 + 256 + lane * 4);
    float s0 = hv.x * w0.x + hv.y * w0.y + hv.z * w0.z + hv.w * w0.w;
    float s1 = hv.x * w1.x + hv.y * w1.y + hv.z * w1.z + hv.w * w1.w;
    for (int off = 32; off; off >>= 1) {
        s0 += __shfl_down(s0, off, 64);
        s1 += __shfl_down(s1, off, 64);
    }
    if (lane == 0) {
        float t0 = s0 + b3[0];
        float t1 = s1 + b3[1];
        float r0 = refpos[row * 2 + 0], r1 = refpos[row * 2 + 1];
        r0 = fminf(fmaxf(r0, -1.f + 1e-5f), 1.f - 1e-5f);
        r1 = fminf(fmaxf(r1, -1.f + 1e-5f), 1.f - 1e-5f);
        refpos[row * 2 + 0] = tanhf(t0 + atanhf(r0));
        refpos[row * 2 + 1] = tanhf(t1 + atanhf(r1));
    }
}

// ---------------------------------------------------------------- final write (dual dtype)
__global__ __launch_bounds__(256) void writeout_kernel(const float* __restrict__ out,
                                                       const float* __restrict__ refpos,
                                                       const int* __restrict__ flag,
                                                       void* __restrict__ o)
{
    int i = blockIdx.x * 256 + threadIdx.x;
    float v;
    if (i < BB * NQ * DD) v = out[i];
    else if (i < BB * NQ * DD + BB * NQ * 2) v = refpos[i - BB * NQ * DD] * 200.f;
    else return;
    if (*flag) ((float*)o)[i] = v;
    else       ((__hip_bfloat16*)o)[i] = __float2bfloat16(v);
}

// ================================================================ launch
extern "C" void kernel_launch(void* const* d_in, const int* in_sizes, int n_in,
                              void* d_out, int out_size, void* d_ws, size_t ws_size,
                              hipStream_t stream)
{
    (void)in_sizes; (void)n_in; (void)out_size;
    static const unsigned SEG[40] = {
        262144, 2048,
        65536, 256, 65536, 256,          // ps
        65536, 256, 65536, 256,          // qp
        589824, 2304, 196608, 768,       // sa_in, sa_out
        196608, 768, 98304, 384,         // off
        196608, 768, 49152, 192,         // aw
        3072, 96,                        // vp
        196608, 768, 196608, 768,        // op
        786432, 3072, 786432, 768,       // ffn
        2304, 2304,                      // ln g,b
        196608, 768, 196608, 768, 1536, 6 // rr
    };
    unsigned cum[41];
    cum[0] = 0;
    for (int i = 0; i < 40; ++i) cum[i + 1] = cum[i] + SEG[i];
    const unsigned TOTAL = cum[40];   // 4,235,174

    Tab tab;
    for (int i = 0; i < 40; ++i) tab.src[i] = d_in[i + 1];
    for (int i = 0; i < 41; ++i) tab.cum[i] = cum[i];

    // ---------------- workspace layout (bytes) ----------------
    char* wsb = (char*)d_ws;
    int*   flag  = (int*)wsb;                       // [0,256)
    float* arena = (float*)(wsb + 256);             // 4,235,174 floats
    float* wsf   = (float*)(wsb + 256 + 16940800);  // padded arena end; 16B aligned
    const size_t SLOT = 2097152;                    // 8192*256 floats
    float* output = wsf + 0 * SLOT;
    float* TG     = wsf + 1 * SLOT;
    float* Kbuf   = wsf + 2 * SLOT;
    float* tB     = wsf + 3 * SLOT;
    float* tA     = wsf + 4 * SLOT;
    float* S1     = wsf + 5 * SLOT;
    float* QP     = wsf + 6 * SLOT;
    float* Qbuf   = wsf + 7 * SLOT;
    float* Vbuf   = wsf + 8 * SLOT;
    float* HID    = S1;                             // FFN hidden overlays slots 5..8
    float* OFFb   = wsf + 9 * SLOT;                 // 8192*128
    float* AWL    = OFFb + (size_t)MROWS * 128;     // 8192*64
    float* REF    = AWL + (size_t)MROWS * 64;       // 8192*2
    const size_t float_end = 256 + 16940800 + (9 * SLOT + (size_t)MROWS * 128 + MROWS * 64 + MROWS * 2) * 4;
    // bevT (bf16) optional
    __hip_bfloat16* bevT = (__hip_bfloat16*)(wsb + ((float_end + 255) & ~(size_t)255));
    const size_t need_bevT = ((float_end + 255) & ~(size_t)255) + 163840000;
    const int useT = (ws_size >= need_bevT) ? 1 : 0;

    const void* bev = d_in[0];
    auto P = [&](int i) { return (const float*)(arena + cum[i]); };
    const float* a_ba   = P(0);  const float* a_rpp = P(1);
    const float* ps_w1  = P(2);  const float* ps_b1 = P(3);
    const float* ps_w2  = P(4);  const float* ps_b2 = P(5);
    const float* qp_w1  = P(6);  const float* qp_b1 = P(7);
    const float* qp_w2  = P(8);  const float* qp_b2 = P(9);
    const float* sa_in_w = P(10); const float* sa_in_b = P(11);
    const float* sa_out_w = P(12); const float* sa_out_b = P(13);
    const float* off_w1 = P(14); const float* off_b1 = P(15);
    const float* off_w2 = P(16); const float* off_b2 = P(17);
    const float* aw_w1  = P(18); const float* aw_b1 = P(19);
    const float* aw_w2  = P(20); const float* aw_b2 = P(21);
    const float* vp_w   = P(22); const float* vp_b  = P(23);
    const float* op_w1  = P(24); const float* op_b1 = P(25);
    const float* op_w2  = P(26); const float* op_b2 = P(27);
    const float* ffn_w1 = P(28); const float* ffn_b1 = P(29);
    const float* ffn_w2 = P(30); const float* ffn_b2 = P(31);
    const float* ln_g   = P(32); const float* ln_b  = P(33);
    const float* rr_w1  = P(34); const float* rr_b1 = P(35);
    const float* rr_w2  = P(36); const float* rr_b2 = P(37);
    const float* rr_w3  = P(38); const float* rr_b3 = P(39);

    auto gemm = [&](const float* A, const float* Wp, const float* bp,
                    float* C, int M, int N, int K, bool relu) {
        dim3 g(N / 64, M / 64);
        if (relu) gemm_kernel<1><<<g, 256, 0, stream>>>(A, Wp, bp, C, M, N, K);
        else      gemm_kernel<0><<<g, 256, 0, stream>>>(A, Wp, bp, C, M, N, K);
    };

    detect_kernel<<<1, 256, 0, stream>>>((const unsigned short*)d_in[1], flag);
    convert_kernel<<<(TOTAL + 255) / 256, 256, 0, stream>>>(tab, flag, arena, TOTAL);
    if (useT) transpose_kernel<<<BB * HH * 8, 256, 0, stream>>>(bev, flag, bevT);
    init_out_kernel<<<MROWS, 256, 0, stream>>>(a_ba, output);
    init_ref_kernel<<<64, 256, 0, stream>>>(a_rpp, REF);

    for (int l = 0; l < NL; ++l) {
        sine_kernel<<<MROWS, 256, 0, stream>>>(REF, S1);
        gemm(output, ps_w1, ps_b1, tA, MROWS, 256, 256, true);
        gemm(tA, ps_w2, ps_b2, QP, MROWS, 256, 256, false);
        gemm(S1, qp_w1, qp_b1, tA, MROWS, 256, 256, true);
        gemm(tA, qp_w2, qp_b2, tB, MROWS, 256, 256, false);
        mul_kernel<<<2048, 256, 0, stream>>>(QP, tB);
        add_kernel<<<2048, 256, 0, stream>>>(S1, output, QP);
        gemm(S1, sa_in_w + (size_t)l * 196608,           sa_in_b + l * 768,       Qbuf, MROWS, 256, 256, false);
        gemm(S1, sa_in_w + (size_t)l * 196608 + 65536,   sa_in_b + l * 768 + 256, Kbuf, MROWS, 256, 256, false);
        gemm(output, sa_in_w + (size_t)l * 196608 + 131072, sa_in_b + l * 768 + 512, Vbuf, MROWS, 256, 256, false);
        attn_kernel<<<256, 256, 0, stream>>>(Qbuf, Kbuf, Vbuf, tA);
        gemm(tA, sa_out_w + (size_t)l * 65536, sa_out_b + l * 256, tB, MROWS, 256, 256, false);
        ln_kernel<<<MROWS, 256, 0, stream>>>(tB, output, ln_g + (l * 3 + 0) * 256, ln_b + (l * 3 + 0) * 256, TG);
        add_kernel<<<2048, 256, 0, stream>>>(S1, TG, QP);
        gemm(S1, off_w1 + (size_t)l * 65536, off_b1 + l * 256, tA, MROWS, 256, 256, true);
        gemm(tA, off_w2 + (size_t)l * 32768, off_b2 + l * 128, OFFb, MROWS, 128, 256, false);
        gemm(S1, aw_w1 + (size_t)l * 65536, aw_b1 + l * 256, tA, MROWS, 256, 256, true);
        gemm(tA, aw_w2 + (size_t)l * 16384, aw_b2 + l * 64, AWL, MROWS, 64, 256, false);
        awsm_kernel<<<256, 256, 0, stream>>>(AWL);
        sample_kernel<<<MROWS, 256, 0, stream>>>(bev, bevT, flag, useT, REF, OFFb, AWL,
                                                 vp_w + (size_t)l * 1024, vp_b + l * 32, Qbuf);
        gemm(Qbuf, op_w1 + (size_t)l * 65536, op_b1 + l * 256, tA, MROWS, 256, 256, true);
        gemm(tA, op_w2 + (size_t)l * 65536, op_b2 + l * 256, tB, MROWS, 256, 256, false);
        ln_kernel<<<MROWS, 256, 0, stream>>>(tB, TG, ln_g + (l * 3 + 1) * 256, ln_b + (l * 3 + 1) * 256, Kbuf);
        gemm(Kbuf, ffn_w1 + (size_t)l * 262144, ffn_b1 + l * 1024, HID, MROWS, 1024, 256, true);
        gemm(HID, ffn_w2 + (size_t)l * 262144, ffn_b2 + l * 256, tB, MROWS, 256, 1024, false);
        ln_kernel<<<MROWS, 256, 0, stream>>>(tB, Kbuf, ln_g + (l * 3 + 2) * 256, ln_b + (l * 3 + 2) * 256, output);
        gemm(output, rr_w1 + (size_t)l * 65536, rr_b1 + l * 256, tA, MROWS, 256, 256, true);
        gemm(tA, rr_w2 + (size_t)l * 65536, rr_b2 + l * 256, tB, MROWS, 256, 256, true);
        refine_kernel<<<2048, 256, 0, stream>>>(tB, rr_w3 + (size_t)l * 512, rr_b3 + l * 2, REF);
    }
    writeout_kernel<<<8256, 256, 0, stream>>>(output, REF, flag, d_out);
}

// Round 3
// 2227.453 us; speedup vs baseline: 1.6341x; 1.6341x over previous
//
#include <hip/hip_runtime.h>
#include <hip/hip_bf16.h>
#include <math.h>

#define DD 256
#define NL 3
#define NHD 8
#define NPT 8
#define HDIM 32
#define NQ 1024
#define BB 8
#define HH 200
#define WW 200
#define MROWS (BB*NQ)   // 8192

typedef __bf16 bf16x4 __attribute__((ext_vector_type(4)));
typedef __bf16 bf16x8 __attribute__((ext_vector_type(8)));
typedef float floatx4 __attribute__((ext_vector_type(4)));
typedef short short8v __attribute__((ext_vector_type(8)));

__device__ __forceinline__ float bu2f(unsigned short u) { return __uint_as_float(((unsigned)u) << 16); }
__device__ __forceinline__ float b2f(const __hip_bfloat16 x) { return __bfloat162float(x); }

// ---------------------------------------------------------------- dtype detect
// bf16 randn data never has exponent-field >= 0xC0; fp32 read as shorts hits ~12%.
__global__ __launch_bounds__(256) void detect_kernel(const unsigned short* __restrict__ ba,
                                                     int* __restrict__ flag)
{
    __shared__ int hit;
    if (threadIdx.x == 0) hit = 0;
    __syncthreads();
    int local = 0;
    for (int i = threadIdx.x; i < 262144; i += 256) {
        unsigned e = (ba[i] >> 7) & 0xFF;
        if (e >= 0xC0) local = 1;
    }
    if (local) atomicOr(&hit, 1);
    __syncthreads();
    if (threadIdx.x == 0) *flag = hit;
}

// ---------------------------------------------------------------- param convert -> bf16 arena
struct Tab {
    const void* src[40];
    unsigned cum[41];
};

__global__ __launch_bounds__(256) void convert_kernel(Tab t, const int* __restrict__ flag,
                                                      unsigned short* __restrict__ arena, unsigned total)
{
    unsigned g = blockIdx.x * 256 + threadIdx.x;
    if (g >= total) return;
    int lo = 0, hi = 39;
    while (lo < hi) {
        int mid = (lo + hi + 1) >> 1;
        if (g >= t.cum[mid]) lo = mid; else hi = mid - 1;
    }
    unsigned idx = g - t.cum[lo];
    if (*flag) {
        float v = ((const float*)t.src[lo])[idx];
        __hip_bfloat16 h = __float2bfloat16(v);
        arena[g] = *(unsigned short*)&h;
    } else {
        arena[g] = ((const unsigned short*)t.src[lo])[idx];
    }
}

// ---------------------------------------------------------------- transpose (optional)
__global__ __launch_bounds__(256) void transpose_kernel(const void* __restrict__ bevv,
                                                        const int* __restrict__ flag,
                                                        __hip_bfloat16* __restrict__ bevT)
{
    const int t = blockIdx.x;
    const int xc = t & 7;
    const int y  = (t >> 3) % HH;
    const int b  = t / (8 * HH);
    const int c  = threadIdx.x;
    const int x0 = xc * 25;
    const size_t src = (((size_t)b * DD + c) * HH + y) * WW + x0;
    const size_t dst = (((size_t)b * HH + y) * WW + x0) * DD + c;
    __hip_bfloat16 tmp[25];
    if (*flag) {
        const float* p = (const float*)bevv;
        #pragma unroll
        for (int x = 0; x < 25; ++x) tmp[x] = __float2bfloat16(p[src + x]);
    } else {
        const __hip_bfloat16* p = (const __hip_bfloat16*)bevv;
        #pragma unroll
        for (int x = 0; x < 25; ++x) tmp[x] = p[src + x];
    }
    #pragma unroll
    for (int x = 0; x < 25; ++x) bevT[dst + (size_t)x * DD] = tmp[x];
}

// ---------------------------------------------------------------- init
__global__ __launch_bounds__(256) void init_out_kernel(const unsigned short* __restrict__ ba,
                                                       float* __restrict__ out)
{
    int i = blockIdx.x * 256 + threadIdx.x;
    out[i] = bu2f(ba[i & (NQ * DD - 1)]);
}

__global__ __launch_bounds__(256) void init_ref_kernel(const unsigned short* __restrict__ rp,
                                                       float* __restrict__ ref)
{
    int i = blockIdx.x * 256 + threadIdx.x;
    ref[i] = tanhf(bu2f(rp[i & (NQ * 2 - 1)]));
}

// ---------------------------------------------------------------- sine embed
__global__ __launch_bounds__(256) void sine_kernel(const float* __restrict__ refpos,
                                                   float* __restrict__ out)
{
    const int bn = blockIdx.x, tid = threadIdx.x;
    const float p = refpos[bn * 2 + (tid < 128 ? 1 : 0)];
    const int j = tid & 127;
    const int k = j >> 1;
    const float t = p * 6.2831853071795864f * exp2f(-(float)k * (4.3219280948873623f / 64.f));
    out[(size_t)bn * DD + tid] = (j & 1) ? cosf(t) : sinf(t);
}

// ---------------------------------------------------------------- MFMA GEMM
// C[M,N] = act(A[M,K](fp32) @ W[N,K]^T(bf16) + bias[N](bf16)); C fp32.
// 64x64 tile, 256 threads = 4 waves; wave w owns rows w*16..w*16+15; 4 acc tiles over N.
template<int RELU_>
__global__ __launch_bounds__(256) void mgemm_kernel(const float* __restrict__ A,
                                                    const unsigned short* __restrict__ W,
                                                    const unsigned short* __restrict__ bias,
                                                    float* __restrict__ C,
                                                    int M, int N, int K)
{
    __shared__ __bf16 As[64][72];   // +8 pad: 144B row stride keeps 16B alignment
    __shared__ __bf16 Bs[64][72];
    const int tid = threadIdx.x;
    const int w = tid >> 6, lane = tid & 63;
    const int quad = lane >> 4, col = lane & 15;
    const int n0 = blockIdx.x * 64, m0 = blockIdx.y * 64;
    floatx4 acc0 = {0.f, 0.f, 0.f, 0.f};
    floatx4 acc1 = acc0, acc2 = acc0, acc3 = acc0;
    for (int k0 = 0; k0 < K; k0 += 64) {
        #pragma unroll
        for (int i = 0; i < 4; ++i) {       // A: 64x64 fp32 -> bf16 LDS
            int idx = i * 256 + tid;
            int row = idx >> 4, cg = idx & 15;
            float4 av = *reinterpret_cast<const float4*>(A + (size_t)(m0 + row) * K + k0 + cg * 4);
            bf16x4 h = { (__bf16)av.x, (__bf16)av.y, (__bf16)av.z, (__bf16)av.w };
            *reinterpret_cast<bf16x4*>(&As[row][cg * 4]) = h;
        }
        #pragma unroll
        for (int i = 0; i < 2; ++i) {       // B: 64x64 bf16 copy
            int idx = i * 256 + tid;
            int row = idx >> 3, cg = idx & 7;
            short8v wv = *reinterpret_cast<const short8v*>(W + (size_t)(n0 + row) * K + k0 + cg * 8);
            *reinterpret_cast<short8v*>(&Bs[row][cg * 8]) = wv;
        }
        __syncthreads();
        #pragma unroll
        for (int kk = 0; kk < 64; kk += 32) {
            bf16x8 af = *reinterpret_cast<const bf16x8*>(&As[w * 16 + col][kk + quad * 8]);
            bf16x8 b0 = *reinterpret_cast<const bf16x8*>(&Bs[ 0 + col][kk + quad * 8]);
            bf16x8 b1 = *reinterpret_cast<const bf16x8*>(&Bs[16 + col][kk + quad * 8]);
            bf16x8 b2 = *reinterpret_cast<const bf16x8*>(&Bs[32 + col][kk + quad * 8]);
            bf16x8 b3 = *reinterpret_cast<const bf16x8*>(&Bs[48 + col][kk + quad * 8]);
            acc0 = __builtin_amdgcn_mfma_f32_16x16x32_bf16(af, b0, acc0, 0, 0, 0);
            acc1 = __builtin_amdgcn_mfma_f32_16x16x32_bf16(af, b1, acc1, 0, 0, 0);
            acc2 = __builtin_amdgcn_mfma_f32_16x16x32_bf16(af, b2, acc2, 0, 0, 0);
            acc3 = __builtin_amdgcn_mfma_f32_16x16x32_bf16(af, b3, acc3, 0, 0, 0);
        }
        __syncthreads();
    }
    floatx4 accs[4] = { acc0, acc1, acc2, acc3 };
    #pragma unroll
    for (int nb = 0; nb < 4; ++nb) {
        const int n = n0 + nb * 16 + col;
        const float bv = bu2f(bias[n]);
        #pragma unroll
        for (int r = 0; r < 4; ++r) {
            float v = accs[nb][r] + bv;
            if (RELU_) v = fmaxf(v, 0.f);
            C[(size_t)(m0 + w * 16 + quad * 4 + r) * N + n] = v;
        }
    }
}

// ---------------------------------------------------------------- elementwise
__global__ __launch_bounds__(256) void mul_kernel(float* __restrict__ a, const float* __restrict__ b)
{
    int i = blockIdx.x * 256 + threadIdx.x;
    float4 x = reinterpret_cast<float4*>(a)[i];
    float4 y = reinterpret_cast<const float4*>(b)[i];
    x.x *= y.x; x.y *= y.y; x.z *= y.z; x.w *= y.w;
    reinterpret_cast<float4*>(a)[i] = x;
}

__global__ __launch_bounds__(256) void add_kernel(float* __restrict__ dst, const float* __restrict__ a,
                                                  const float* __restrict__ b)
{
    int i = blockIdx.x * 256 + threadIdx.x;
    float4 x = reinterpret_cast<const float4*>(a)[i];
    float4 y = reinterpret_cast<const float4*>(b)[i];
    x.x += y.x; x.y += y.y; x.z += y.z; x.w += y.w;
    reinterpret_cast<float4*>(dst)[i] = x;
}

// ---------------------------------------------------------------- self-attention
// 1024 threads: thread = (query q8, key-quarter kc). 256-key K/V stages in LDS
// shared by all quarters; online-softmax partials merged via LDS at the end.
__global__ __launch_bounds__(1024) void attn_kernel(const float* __restrict__ Q,
                                                    const float* __restrict__ Kb,
                                                    const float* __restrict__ Vb,
                                                    float* __restrict__ O)
{
    __shared__ float ldsf[16384];                    // 64 KB
    float (*Ks)[32] = (float(*)[32])ldsf;            // [0, 8192)
    float (*Vs)[32] = (float(*)[32])(ldsf + 8192);   // [8192, 16384)
    const int tid = threadIdx.x;
    const int q8 = tid & 255, kc = tid >> 8;
    const int bid = blockIdx.x;
    const int bh = bid >> 2, qc = bid & 3;
    const int b = bh >> 3, h = bh & 7;
    const int n = qc * 256 + q8;
    const size_t qbase = ((size_t)(b * NQ + n)) * DD + h * HDIM;
    float q[32];
    #pragma unroll
    for (int dv = 0; dv < 8; ++dv) {
        float4 qq = *reinterpret_cast<const float4*>(Q + qbase + dv * 4);
        q[dv * 4 + 0] = qq.x * 0.17677669529663687f;
        q[dv * 4 + 1] = qq.y * 0.17677669529663687f;
        q[dv * 4 + 2] = qq.z * 0.17677669529663687f;
        q[dv * 4 + 3] = qq.w * 0.17677669529663687f;
    }
    float m = -3.0e38f, lsum = 0.f;
    float acc[32] = {0.f};
    for (int t = 0; t < 4; ++t) {
        #pragma unroll
        for (int i = 0; i < 8; ++i) {
            int idx = i * 1024 + tid;
            int j = idx >> 5, d = idx & 31;
            size_t g = ((size_t)(b * NQ + t * 256 + j)) * DD + h * HDIM + d;
            Ks[j][d] = Kb[g];
            Vs[j][d] = Vb[g];
        }
        __syncthreads();
        for (int jj = 0; jj < 64; ++jj) {
            const int j = kc * 64 + jj;
            float s0 = 0.f, s1 = 0.f, s2 = 0.f, s3 = 0.f;
            #pragma unroll
            for (int dv = 0; dv < 8; ++dv) {
                float4 kv = reinterpret_cast<const float4*>(&Ks[j][0])[dv];
                s0 = fmaf(q[dv * 4 + 0], kv.x, s0);
                s1 = fmaf(q[dv * 4 + 1], kv.y, s1);
                s2 = fmaf(q[dv * 4 + 2], kv.z, s2);
                s3 = fmaf(q[dv * 4 + 3], kv.w, s3);
            }
            float s = (s0 + s1) + (s2 + s3);
            if (s > m) {
                float corr = __expf(m - s);
                lsum *= corr;
                #pragma unroll
                for (int d = 0; d < 32; ++d) acc[d] *= corr;
                m = s;
            }
            float p = __expf(s - m);
            lsum += p;
            #pragma unroll
            for (int dv = 0; dv < 8; ++dv) {
                float4 vv = reinterpret_cast<const float4*>(&Vs[j][0])[dv];
                acc[dv * 4 + 0] = fmaf(p, vv.x, acc[dv * 4 + 0]);
                acc[dv * 4 + 1] = fmaf(p, vv.y, acc[dv * 4 + 1]);
                acc[dv * 4 + 2] = fmaf(p, vv.z, acc[dv * 4 + 2]);
                acc[dv * 4 + 3] = fmaf(p, vv.w, acc[dv * 4 + 3]);
            }
        }
        __syncthreads();
    }
    // merge partials across kc (overlay MB on Ks/Vs region — all dead now)
    float (*MB)[34] = (float(*)[34])ldsf;
    for (int r = 1; r < 4; ++r) {
        if (kc == r) {
            MB[q8][0] = m; MB[q8][1] = lsum;
            #pragma unroll
            for (int d = 0; d < 32; ++d) MB[q8][2 + d] = acc[d];
        }
        __syncthreads();
        if (kc == 0) {
            float m2 = MB[q8][0], l2 = MB[q8][1];
            float nm = fmaxf(m, m2);
            float a1 = __expf(m - nm), a2 = __expf(m2 - nm);
            lsum = lsum * a1 + l2 * a2;
            #pragma unroll
            for (int d = 0; d < 32; ++d) acc[d] = acc[d] * a1 + MB[q8][2 + d] * a2;
            m = nm;
        }
        __syncthreads();
    }
    if (kc == 0) {
        float inv = 1.f / lsum;
        #pragma unroll
        for (int d = 0; d < 32; ++d) O[qbase + d] = acc[d] * inv;
    }
}

// ---------------------------------------------------------------- layernorm of (X+R)
__global__ __launch_bounds__(256) void ln_kernel(const float* __restrict__ X,
                                                 const float* __restrict__ R,
                                                 const unsigned short* __restrict__ g,
                                                 const unsigned short* __restrict__ bta,
                                                 float* __restrict__ Y)
{
    __shared__ float red[4], red2[4];
    const int row = blockIdx.x, tid = threadIdx.x;
    float x = X[(size_t)row * DD + tid] + R[(size_t)row * DD + tid];
    float s = x;
    for (int off = 32; off; off >>= 1) s += __shfl_down(s, off, 64);
    const int wid = tid >> 6, lane = tid & 63;
    if (lane == 0) red[wid] = s;
    __syncthreads();
    float mean = (red[0] + red[1] + red[2] + red[3]) * (1.f / 256.f);
    float c = x - mean;
    float s2 = c * c;
    for (int off = 32; off; off >>= 1) s2 += __shfl_down(s2, off, 64);
    if (lane == 0) red2[wid] = s2;
    __syncthreads();
    float var = (red2[0] + red2[1] + red2[2] + red2[3]) * (1.f / 256.f);
    Y[(size_t)row * DD + tid] = c * rsqrtf(var + 1e-5f) * bu2f(g[tid]) + bu2f(bta[tid]);
}

// ---------------------------------------------------------------- aw softmax over P=8
__global__ __launch_bounds__(256) void awsm_kernel(float* __restrict__ awl)
{
    int i = blockIdx.x * 256 + threadIdx.x;
    size_t base = (size_t)i * 8;
    float v[8];
    float mx = -3.0e38f;
    #pragma unroll
    for (int p = 0; p < 8; ++p) { v[p] = awl[base + p]; mx = fmaxf(mx, v[p]); }
    float ssum = 0.f;
    #pragma unroll
    for (int p = 0; p < 8; ++p) { v[p] = __expf(v[p] - mx); ssum += v[p]; }
    float inv = 1.f / ssum;
    #pragma unroll
    for (int p = 0; p < 8; ++p) awl[base + p] = v[p] * inv;
}

// ---------------------------------------------------------------- deformable sampling
__global__ __launch_bounds__(256) void sample_kernel(const void* __restrict__ bevraw,
                                                     const __hip_bfloat16* __restrict__ bevT,
                                                     const int* __restrict__ flag, int useT,
                                                     const float* __restrict__ refpos,
                                                     const float* __restrict__ OFF,
                                                     const float* __restrict__ AW,
                                                     const unsigned short* __restrict__ vpw,
                                                     const unsigned short* __restrict__ vpb,
                                                     float* __restrict__ CA)
{
    __shared__ float vpsT[1024];   // vpsT[cc*32+c'] = vpw[c'][cc]
    __shared__ float vpbs[32];
    __shared__ float aggs[256];
    const int bn = blockIdx.x;
    const int b = bn >> 10;
    const int tid = threadIdx.x;
    const int h = tid >> 5, c = tid & 31;
    const int mode = useT ? 2 : (*flag ? 1 : 0);
    for (int idx = tid; idx < 1024; idx += 256)
        vpsT[idx] = bu2f(vpw[(idx & 31) * 32 + (idx >> 5)]);
    if (tid < 32) vpbs[tid] = bu2f(vpb[tid]);
    const float rx = refpos[bn * 2 + 0], ry = refpos[bn * 2 + 1];
    const float* fbev = (const float*)bevraw;
    const __hip_bfloat16* hbev = (const __hip_bfloat16*)bevraw;
    float agg = 0.f;
    #pragma unroll
    for (int p = 0; p < 8; ++p) {
        const float ox = OFF[(size_t)bn * 128 + h * 16 + p * 2 + 0];
        const float oy = OFF[(size_t)bn * 128 + h * 16 + p * 2 + 1];
        const float a = AW[(size_t)bn * 64 + h * 8 + p];
        float x = (rx + ox * (1.f / 200.f) + 1.f) * 100.f - 0.5f;
        float y = (ry + oy * (1.f / 200.f) + 1.f) * 100.f - 0.5f;
        float x0f = floorf(x), y0f = floorf(y);
        int x0 = (int)x0f, y0 = (int)y0f;
        float wx1 = x - x0f, wx0 = 1.f - wx1;
        float wy1 = y - y0f, wy0 = 1.f - wy1;
        int xs[2] = { x0, x0 + 1 };
        int ys[2] = { y0, y0 + 1 };
        float wxs[2] = { wx0, wx1 };
        float wys[2] = { wy0, wy1 };
        float v = 0.f;
        #pragma unroll
        for (int cy = 0; cy < 2; ++cy)
            #pragma unroll
            for (int cx = 0; cx < 2; ++cx) {
                int xi = xs[cx], yi = ys[cy];
                if (xi >= 0 && xi < WW && yi >= 0 && yi < HH) {
                    float val;
                    if (mode == 2)
                        val = b2f(bevT[(((size_t)(b * HH + yi)) * WW + xi) * DD + h * HDIM + c]);
                    else {
                        size_t addr = (((size_t)(b * DD + h * HDIM + c)) * HH + yi) * WW + xi;
                        val = (mode == 1) ? fbev[addr] : b2f(hbev[addr]);
                    }
                    v = fmaf(wxs[cx] * wys[cy], val, v);
                }
            }
        agg = fmaf(a, v, agg);
    }
    aggs[tid] = agg;
    __syncthreads();
    float o = vpbs[c];
    #pragma unroll
    for (int cc = 0; cc < 32; ++cc)
        o = fmaf(vpsT[cc * 32 + c], aggs[h * 32 + cc], o);
    CA[(size_t)bn * DD + tid] = o;
}

// ---------------------------------------------------------------- ref_pos refine
__global__ __launch_bounds__(256) void refine_kernel(const float* __restrict__ H2,
                                                     const unsigned short* __restrict__ w3,
                                                     const unsigned short* __restrict__ b3,
                                                     float* __restrict__ refpos)
{
    const int tid = threadIdx.x;
    const int wid = tid >> 6, lane = tid & 63;
    const int row = blockIdx.x * 4 + wid;
    const float4 hv = *reinterpret_cast<const float4*>(H2 + (size_t)row * DD + lane * 4);
    ushort4 w0 = *reinterpret_cast<const ushort4*>(w3 + lane * 4);
    ushort4 w1 = *reinterpret_cast<const ushort4*>(w3 + 256 + lane * 4);
    float s0 = hv.x * bu2f(w0.x) + hv.y * bu2f(w0.y) + hv.z * bu2f(w0.z) + hv.w * bu2f(w0.w);
    float s1 = hv.x * bu2f(w1.x) + hv.y * bu2f(w1.y) + hv.z * bu2f(w1.z) + hv.w * bu2f(w1.w);
    for (int off = 32; off; off >>= 1) {
        s0 += __shfl_down(s0, off, 64);
        s1 += __shfl_down(s1, off, 64);
    }
    if (lane == 0) {
        float t0 = s0 + bu2f(b3[0]);
        float t1 = s1 + bu2f(b3[1]);
        float r0 = refpos[row * 2 + 0], r1 = refpos[row * 2 + 1];
        r0 = fminf(fmaxf(r0, -1.f + 1e-5f), 1.f - 1e-5f);
        r1 = fminf(fmaxf(r1, -1.f + 1e-5f), 1.f - 1e-5f);
        refpos[row * 2 + 0] = tanhf(t0 + atanhf(r0));
        refpos[row * 2 + 1] = tanhf(t1 + atanhf(r1));
    }
}

// ---------------------------------------------------------------- final write (dual dtype)
__global__ __launch_bounds__(256) void writeout_kernel(const float* __restrict__ out,
                                                       const float* __restrict__ refpos,
                                                       const int* __restrict__ flag,
                                                       void* __restrict__ o)
{
    int i = blockIdx.x * 256 + threadIdx.x;
    float v;
    if (i < BB * NQ * DD) v = out[i];
    else if (i < BB * NQ * DD + BB * NQ * 2) v = refpos[i - BB * NQ * DD] * 200.f;
    else return;
    if (*flag) ((float*)o)[i] = v;
    else       ((__hip_bfloat16*)o)[i] = __float2bfloat16(v);
}

// ================================================================ launch
extern "C" void kernel_launch(void* const* d_in, const int* in_sizes, int n_in,
                              void* d_out, int out_size, void* d_ws, size_t ws_size,
                              hipStream_t stream)
{
    (void)in_sizes; (void)n_in; (void)out_size;
    static const unsigned SEG[40] = {
        262144, 2048,
        65536, 256, 65536, 256,          // ps
        65536, 256, 65536, 256,          // qp
        589824, 2304, 196608, 768,       // sa_in, sa_out
        196608, 768, 98304, 384,         // off
        196608, 768, 49152, 192,         // aw
        3072, 96,                        // vp
        196608, 768, 196608, 768,        // op
        786432, 3072, 786432, 768,       // ffn
        2304, 2304,                      // ln g,b
        196608, 768, 196608, 768, 1536, 6 // rr
    };
    unsigned cum[41];
    cum[0] = 0;
    for (int i = 0; i < 40; ++i) cum[i + 1] = cum[i] + SEG[i];
    const unsigned TOTAL = cum[40];   // 4,235,174

    Tab tab;
    for (int i = 0; i < 40; ++i) tab.src[i] = d_in[i + 1];
    for (int i = 0; i < 41; ++i) tab.cum[i] = cum[i];

    // ---------------- workspace layout ----------------
    char* wsb = (char*)d_ws;
    int*   flag  = (int*)wsb;                              // [0,256)
    unsigned short* arenaH = (unsigned short*)(wsb + 256); // bf16 params, 8,470,348 B
    float* wsf   = (float*)(wsb + 256 + 8470528);          // 256-aligned past arena
    const size_t SLOT = 2097152;                           // 8192*256 floats
    float* output = wsf + 0 * SLOT;
    float* TG     = wsf + 1 * SLOT;
    float* Kbuf   = wsf + 2 * SLOT;
    float* tB     = wsf + 3 * SLOT;
    float* tA     = wsf + 4 * SLOT;
    float* S1     = wsf + 5 * SLOT;
    float* QP     = wsf + 6 * SLOT;
    float* Qbuf   = wsf + 7 * SLOT;
    float* Vbuf   = wsf + 8 * SLOT;
    float* HID    = S1;                                    // FFN hidden overlays slots 5..8
    float* OFFb   = wsf + 9 * SLOT;
    float* AWL    = OFFb + (size_t)MROWS * 128;
    float* REF    = AWL + (size_t)MROWS * 64;
    const size_t float_end = 256 + 8470528 +
        (9 * SLOT + (size_t)MROWS * 128 + MROWS * 64 + MROWS * 2) * 4;
    __hip_bfloat16* bevT = (__hip_bfloat16*)(wsb + ((float_end + 255) & ~(size_t)255));
    const size_t need_bevT = ((float_end + 255) & ~(size_t)255) + 163840000;
    const int useT = (ws_size >= need_bevT) ? 1 : 0;

    const void* bev = d_in[0];
    auto P = [&](int i) { return (const unsigned short*)(arenaH + cum[i]); };
    const unsigned short* a_ba  = P(0);  const unsigned short* a_rpp = P(1);
    const unsigned short* ps_w1 = P(2);  const unsigned short* ps_b1 = P(3);
    const unsigned short* ps_w2 = P(4);  const unsigned short* ps_b2 = P(5);
    const unsigned short* qp_w1 = P(6);  const unsigned short* qp_b1 = P(7);
    const unsigned short* qp_w2 = P(8);  const unsigned short* qp_b2 = P(9);
    const unsigned short* sa_in_w = P(10); const unsigned short* sa_in_b = P(11);
    const unsigned short* sa_out_w = P(12); const unsigned short* sa_out_b = P(13);
    const unsigned short* off_w1 = P(14); const unsigned short* off_b1 = P(15);
    const unsigned short* off_w2 = P(16); const unsigned short* off_b2 = P(17);
    const unsigned short* aw_w1  = P(18); const unsigned short* aw_b1 = P(19);
    const unsigned short* aw_w2  = P(20); const unsigned short* aw_b2 = P(21);
    const unsigned short* vp_w   = P(22); const unsigned short* vp_b  = P(23);
    const unsigned short* op_w1  = P(24); const unsigned short* op_b1 = P(25);
    const unsigned short* op_w2  = P(26); const unsigned short* op_b2 = P(27);
    const unsigned short* ffn_w1 = P(28); const unsigned short* ffn_b1 = P(29);
    const unsigned short* ffn_w2 = P(30); const unsigned short* ffn_b2 = P(31);
    const unsigned short* ln_g   = P(32); const unsigned short* ln_b  = P(33);
    const unsigned short* rr_w1  = P(34); const unsigned short* rr_b1 = P(35);
    const unsigned short* rr_w2  = P(36); const unsigned short* rr_b2 = P(37);
    const unsigned short* rr_w3  = P(38); const unsigned short* rr_b3 = P(39);

    auto gemm = [&](const float* A, const unsigned short* Wp, const unsigned short* bp,
                    float* C, int M, int N, int K, bool relu) {
        dim3 g(N / 64, M / 64);
        if (relu) mgemm_kernel<1><<<g, 256, 0, stream>>>(A, Wp, bp, C, M, N, K);
        else      mgemm_kernel<0><<<g, 256, 0, stream>>>(A, Wp, bp, C, M, N, K);
    };

    detect_kernel<<<1, 256, 0, stream>>>((const unsigned short*)d_in[1], flag);
    convert_kernel<<<(TOTAL + 255) / 256, 256, 0, stream>>>(tab, flag, arenaH, TOTAL);
    if (useT) transpose_kernel<<<BB * HH * 8, 256, 0, stream>>>(bev, flag, bevT);
    init_out_kernel<<<MROWS, 256, 0, stream>>>(a_ba, output);
    init_ref_kernel<<<64, 256, 0, stream>>>(a_rpp, REF);

    for (int l = 0; l < NL; ++l) {
        sine_kernel<<<MROWS, 256, 0, stream>>>(REF, S1);
        gemm(output, ps_w1, ps_b1, tA, MROWS, 256, 256, true);
        gemm(tA, ps_w2, ps_b2, QP, MROWS, 256, 256, false);
        gemm(S1, qp_w1, qp_b1, tA, MROWS, 256, 256, true);
        gemm(tA, qp_w2, qp_b2, tB, MROWS, 256, 256, false);
        mul_kernel<<<2048, 256, 0, stream>>>(QP, tB);
        add_kernel<<<2048, 256, 0, stream>>>(S1, output, QP);
        gemm(S1, sa_in_w + (size_t)l * 196608,            sa_in_b + l * 768,       Qbuf, MROWS, 256, 256, false);
        gemm(S1, sa_in_w + (size_t)l * 196608 + 65536,    sa_in_b + l * 768 + 256, Kbuf, MROWS, 256, 256, false);
        gemm(output, sa_in_w + (size_t)l * 196608 + 131072, sa_in_b + l * 768 + 512, Vbuf, MROWS, 256, 256, false);
        attn_kernel<<<256, 1024, 0, stream>>>(Qbuf, Kbuf, Vbuf, tA);
        gemm(tA, sa_out_w + (size_t)l * 65536, sa_out_b + l * 256, tB, MROWS, 256, 256, false);
        ln_kernel<<<MROWS, 256, 0, stream>>>(tB, output, ln_g + (l * 3 + 0) * 256, ln_b + (l * 3 + 0) * 256, TG);
        add_kernel<<<2048, 256, 0, stream>>>(S1, TG, QP);
        gemm(S1, off_w1 + (size_t)l * 65536, off_b1 + l * 256, tA, MROWS, 256, 256, true);
        gemm(tA, off_w2 + (size_t)l * 32768, off_b2 + l * 128, OFFb, MROWS, 128, 256, false);
        gemm(S1, aw_w1 + (size_t)l * 65536, aw_b1 + l * 256, tA, MROWS, 256, 256, true);
        gemm(tA, aw_w2 + (size_t)l * 16384, aw_b2 + l * 64, AWL, MROWS, 64, 256, false);
        awsm_kernel<<<256, 256, 0, stream>>>(AWL);
        sample_kernel<<<MROWS, 256, 0, stream>>>(bev, bevT, flag, useT, REF, OFFb, AWL,
                                                 vp_w + (size_t)l * 1024, vp_b + l * 32, Qbuf);
        gemm(Qbuf, op_w1 + (size_t)l * 65536, op_b1 + l * 256, tA, MROWS, 256, 256, true);
        gemm(tA, op_w2 + (size_t)l * 65536, op_b2 + l * 256, tB, MROWS, 256, 256, false);
        ln_kernel<<<MROWS, 256, 0, stream>>>(tB, TG, ln_g + (l * 3 + 1) * 256, ln_b + (l * 3 + 1) * 256, Kbuf);
        gemm(Kbuf, ffn_w1 + (size_t)l * 262144, ffn_b1 + l * 1024, HID, MROWS, 1024, 256, true);
        gemm(HID, ffn_w2 + (size_t)l * 262144, ffn_b2 + l * 256, tB, MROWS, 256, 1024, false);
        ln_kernel<<<MROWS, 256, 0, stream>>>(tB, Kbuf, ln_g + (l * 3 + 2) * 256, ln_b + (l * 3 + 2) * 256, output);
        gemm(output, rr_w1 + (size_t)l * 65536, rr_b1 + l * 256, tA, MROWS, 256, 256, true);
        gemm(tA, rr_w2 + (size_t)l * 65536, rr_b2 + l * 256, tB, MROWS, 256, 256, true);
        refine_kernel<<<2048, 256, 0, stream>>>(tB, rr_w3 + (size_t)l * 512, rr_b3 + l * 2, REF);
    }
    writeout_kernel<<<8256, 256, 0, stream>>>(output, REF, flag, d_out);
}